// Round 8
// baseline (455.513 us; speedup 1.0000x reference)
//
#include <hip/hip_runtime.h>
#include <math.h>

#define BATCH 8
#define SEQ   2048
#define DIM   512
#define NTH   512

typedef unsigned int u32;
typedef _Float16 h2  __attribute__((ext_vector_type(2)));
typedef _Float16 h8  __attribute__((ext_vector_type(8)));
typedef float    f4  __attribute__((ext_vector_type(4)));
typedef u32      u2v __attribute__((ext_vector_type(2)));
typedef u32      u4v __attribute__((ext_vector_type(4)));

#define MFMA16(a,b,c) __builtin_amdgcn_mfma_f32_16x16x32_f16((a),(b),(c),0,0,0)

#if __has_builtin(__builtin_amdgcn_cvt_pkrtz)
__device__ __forceinline__ u32 pack2(float a, float b) {
    return __builtin_bit_cast(u32, __builtin_amdgcn_cvt_pkrtz(a, b));
}
__device__ __forceinline__ void split2(float a, float b, u32& hi, u32& lo) {
    h2 th = __builtin_bit_cast(h2, __builtin_amdgcn_cvt_pkrtz(a, b));
    hi = __builtin_bit_cast(u32, th);
    // residual of RTZ hi fits lo with ~2^-20 rel total error: fp32-class scores
    lo = __builtin_bit_cast(u32, __builtin_amdgcn_cvt_pkrtz(a - (float)th[0], b - (float)th[1]));
}
#else
__device__ __forceinline__ u32 pack2(float a, float b) {
    h2 t; t[0] = (_Float16)a; t[1] = (_Float16)b;
    return __builtin_bit_cast(u32, t);
}
__device__ __forceinline__ void split2(float a, float b, u32& hi, u32& lo) {
    _Float16 ha = (_Float16)a, hb = (_Float16)b;
    h2 th; th[0] = ha; th[1] = hb; hi = __builtin_bit_cast(u32, th);
    h2 tl; tl[0] = (_Float16)(a - (float)ha); tl[1] = (_Float16)(b - (float)hb);
    lo = __builtin_bit_cast(u32, tl);
}
#endif

// 512 threads = 8 waves. Wave pair (wp, h): wp=w&3 -> Q rows 16wp..+15;
// h=w>>2 -> d-half (QK k-split, PV output-d split). Fragment maps R6-validated:
//   A: row=lane&15, slot e <-> k = 8*lg + e (per 32-k window)
//   B: col=lane&15, same slot map;  C/D: row=4*lg+reg, col=lane&15
__global__ __launch_bounds__(NTH, 2)
void attn_kernel(const float* __restrict__ Q, const float* __restrict__ K,
                 const float* __restrict__ V, const int* __restrict__ mfp,
                 float* __restrict__ Out)
{
    __shared__ u32 KTh[2][128][20];                           // 20.5 KB (pair-packed K hi)
    __shared__ u32 KTl[2][128][20];                           // 20.5 KB (lo)
    __shared__ union { float sx[64][132]; u32 vt[2][32][96]; } SV;  // 33.8 KB (S-exchange / V)
    __shared__ u32  Pp[64][68];                               // 17.4 KB
    __shared__ float fsx[64];
    __shared__ float lsx[64];

    const int tid  = threadIdx.x;
    const int w    = tid >> 6;
    const int wp   = w & 3;            // row group
    const int h    = w >> 2;           // d-half
    const int lane = tid & 63;
    const int lx   = lane & 15;
    const int lg   = lane >> 4;
    const int b    = blockIdx.x >> 5;
    const int m0   = (blockIdx.x & 31) * 64;
    const int mf   = mfp[0];

    // staging maps
    const int ksr = tid >> 2;          // K: row 0..127
    const int khf = (tid >> 1) & 1;    // K: half
    const int kqp = tid & 1;           // K: 16-d subspan
    const int spp = tid >> 4;          // V: s-quad 0..31 (rows 4spp..+3)
    const int dq  = tid & 15;
    const int vhf = dq >> 3;           // V: half
    const int dl4 = 4 * (dq & 7);      // V: d-local base (within 32-d chunk)

    const float* __restrict__ Qb = Q + (size_t)b * SEQ * DIM;
    const float* __restrict__ Kb = K + (size_t)b * SEQ * DIM;
    const float* __restrict__ Vb = V + (size_t)b * SEQ * DIM;

    // ---- Q fragments in registers (own d-half, hi/lo split): 64 VGPR ----
    h8 qh[8], ql[8];
    {
        const float* qrowp = Qb + (size_t)(m0 + 16 * wp + lx) * DIM;
        #pragma unroll
        for (int i = 0; i < 8; i++) {
            float bufv[8];
            *(float4*)&bufv[0] = *(const float4*)(qrowp + 256 * h + 32 * i + 8 * lg);
            *(float4*)&bufv[4] = *(const float4*)(qrowp + 256 * h + 32 * i + 8 * lg + 4);
            u4v uh, ul;
            #pragma unroll
            for (int p = 0; p < 4; p++) { u32 hi, lo; split2(bufv[2*p], bufv[2*p+1], hi, lo); uh[p] = hi; ul[p] = lo; }
            qh[i] = __builtin_bit_cast(h8, uh);
            ql[i] = __builtin_bit_cast(h8, ul);
        }
    }

    f4 o[16];
    const f4 fz = {0.f, 0.f, 0.f, 0.f};
    #pragma unroll
    for (int i = 0; i < 16; i++) o[i] = fz;
    float m_run[4] = {-INFINITY, -INFINITY, -INFINITY, -INFINITY};
    float l_run[4] = {0.f, 0.f, 0.f, 0.f};

    const float dk = 22.627416997969522f;   // sqrt(512)

    for (int s0 = 0; s0 < SEQ; s0 += 128) {
        // ============ S = Q K^T partial over own 256-d half ============
        f4 sa[8];
        #pragma unroll
        for (int nt = 0; nt < 8; nt++) sa[nt] = fz;

        float4 kreg[4];
        #pragma unroll
        for (int c = 0; c < 4; c++)
            kreg[c] = *(const float4*)(Kb + (size_t)(s0 + ksr) * DIM + 256 * khf + 16 * kqp + 4 * c);

        #pragma unroll
        for (int i = 0; i < 8; i++) {
            __syncthreads();   // (A) KT region free
            {
                u32 hi[8], lo[8];
                #pragma unroll
                for (int j = 0; j < 4; j++) {
                    split2(kreg[j].x, kreg[j].y, hi[2*j],   lo[2*j]);
                    split2(kreg[j].z, kreg[j].w, hi[2*j+1], lo[2*j+1]);
                }
                u4v a0 = {hi[0],hi[1],hi[2],hi[3]}, a1 = {hi[4],hi[5],hi[6],hi[7]};
                u4v b0 = {lo[0],lo[1],lo[2],lo[3]}, b1 = {lo[4],lo[5],lo[6],lo[7]};
                *(u4v*)&KTh[khf][ksr][8 * kqp]     = a0;
                *(u4v*)&KTh[khf][ksr][8 * kqp + 4] = a1;
                *(u4v*)&KTl[khf][ksr][8 * kqp]     = b0;
                *(u4v*)&KTl[khf][ksr][8 * kqp + 4] = b1;
            }
            __syncthreads();   // (B) staged chunk visible
            if (i < 7) {
                #pragma unroll
                for (int c = 0; c < 4; c++)
                    kreg[c] = *(const float4*)(Kb + (size_t)(s0 + ksr) * DIM
                                               + 256 * khf + 32 * (i + 1) + 16 * kqp + 4 * c);
            }
            #pragma unroll
            for (int nt = 0; nt < 8; nt++) {
                const u4v uh = *(const u4v*)&KTh[h][16 * nt + lx][4 * lg];
                const u4v ul = *(const u4v*)&KTl[h][16 * nt + lx][4 * lg];
                const h8 kh = __builtin_bit_cast(h8, uh);
                const h8 kl = __builtin_bit_cast(h8, ul);
                sa[nt] = MFMA16(qh[i], kh, sa[nt]);
                sa[nt] = MFMA16(qh[i], kl, sa[nt]);
                sa[nt] = MFMA16(ql[i], kh, sa[nt]);
            }
        }

        // V prefetch for PV iter 0 (overlaps the whole softmax phase)
        float4 vreg[4];
        #pragma unroll
        for (int r = 0; r < 4; r++)
            vreg[r] = *(const float4*)(Vb + (size_t)(s0 + 4 * spp + r) * DIM + 256 * vhf + dl4);

        // ============ S-merge + softmax (h1 owns), R6-verbatim math ============
        if (h == 0) {
            #pragma unroll
            for (int nt = 0; nt < 8; nt++)
                #pragma unroll
                for (int r = 0; r < 4; r++)
                    SV.sx[16 * wp + 4 * lg + r][16 * nt + lx] = sa[nt][r];
        }
        __syncthreads();   // (C)

        float fscale[4];
        if (h == 1) {
            float pw[4][8];
            #pragma unroll
            for (int nt = 0; nt < 8; nt++)
                #pragma unroll
                for (int r = 0; r < 4; r++) {
                    float s = sa[nt][r] + SV.sx[16 * wp + 4 * lg + r][16 * nt + lx];
                    s = (s == s) ? s : 0.0f;                       // NaN scrub
                    sa[nt][r] = fminf(fmaxf(s, -2.0e4f), 2.0e4f);  // overflow-proof
                }
            #pragma unroll
            for (int r = 0; r < 4; r++) {
                const int tg = m0 + 16 * wp + 4 * lg + r;
                float z[8]; float zm = -INFINITY;
                #pragma unroll
                for (int nt = 0; nt < 8; nt++) {
                    const int sg = s0 + nt * 16 + lx;
                    const float mult = (mf && sg >= tg) ? -1.0e9f : 1.0f;
                    z[nt] = sa[nt][r] * mult / dk;
                    zm = fmaxf(zm, z[nt]);
                }
                #pragma unroll
                for (int mm = 1; mm < 16; mm <<= 1) zm = fmaxf(zm, __shfl_xor(zm, mm));
                const float mnew = fmaxf(m_run[r], zm);
                float ps = 0.f;
                #pragma unroll
                for (int nt = 0; nt < 8; nt++) {
                    const float p = __expf(z[nt] - mnew);
                    pw[r][nt] = p; ps += p;
                }
                #pragma unroll
                for (int mm = 1; mm < 16; mm <<= 1) ps += __shfl_xor(ps, mm);
                const float fs = __expf(m_run[r] - mnew);   // first tile: 0
                fscale[r] = fs;
                l_run[r]  = l_run[r] * fs + ps;
                m_run[r]  = mnew;
                if (lx == 0) fsx[16 * wp + 4 * lg + r] = fs;
            }
            // P -> Pp pair-packed (R6-verbatim shfl pairing)
            #pragma unroll
            for (int r = 0; r < 4; r++)
                #pragma unroll
                for (int nt = 0; nt < 8; nt++) {
                    const float self = pw[r][nt];
                    const float nb   = __shfl_xor(self, 1);
                    if (!(lx & 1))
                        Pp[16 * wp + 4 * lg + r][8 * nt + (lx >> 1)] = pack2(self, nb);
                }
        }
        __syncthreads();   // (D) Pp + fsx visible

        if (h == 0) {
            #pragma unroll
            for (int r = 0; r < 4; r++) fscale[r] = fsx[16 * wp + 4 * lg + r];
        }
        #pragma unroll
        for (int i = 0; i < 16; i++) {
            f4 t = o[i];
            t[0] *= fscale[0]; t[1] *= fscale[1]; t[2] *= fscale[2]; t[3] *= fscale[3];
            o[i] = t;
        }

        // ============ O += P V over own d-half ============
        h8 pa[4];
        #pragma unroll
        for (int i = 0; i < 8; i++) {
            __syncthreads();   // (E) VT region free
            #pragma unroll
            for (int e = 0; e < 4; e++) {
                const int dloc = dl4 + e;
                const int pos  = (2 * spp) ^ (4 * (dloc & 7));
                u2v val = { pack2(vreg[0][e], vreg[1][e]), pack2(vreg[2][e], vreg[3][e]) };
                *(u2v*)&SV.vt[vhf][dloc][pos] = val;
            }
            __syncthreads();   // (F) staged V chunk visible
            if (i < 7) {
                #pragma unroll
                for (int r = 0; r < 4; r++)
                    vreg[r] = *(const float4*)(Vb + (size_t)(s0 + 4 * spp + r) * DIM
                                               + 256 * vhf + 32 * (i + 1) + dl4);
            }
            if (i == 0) {
                #pragma unroll
                for (int k = 0; k < 4; k++)
                    pa[k] = __builtin_bit_cast(h8, *(const u4v*)&Pp[16 * wp + lx][16 * k + 4 * lg]);
            }
            #pragma unroll
            for (int dt = 0; dt < 2; dt++) {
                const int dloc = 16 * dt + lx;
                const int ff   = 4 * (lx & 7);
                #pragma unroll
                for (int k = 0; k < 4; k++) {
                    const u4v uv = *(const u4v*)&SV.vt[h][dloc][(16 * k + 4 * lg) ^ ff];
                    o[2 * i + dt] = MFMA16(pa[k], __builtin_bit_cast(h8, uv), o[2 * i + dt]);
                }
            }
        }
    }

    // ================= epilogue =================
    if (h == 1) {
        #pragma unroll
        for (int r = 0; r < 4; r++)
            if (lx == 0) lsx[16 * wp + 4 * lg + r] = l_run[r];
    }
    __syncthreads();
    float il[4];
    #pragma unroll
    for (int r = 0; r < 4; r++)
        il[r] = 1.0f / ((h == 1) ? l_run[r] : lsx[16 * wp + 4 * lg + r]);
    #pragma unroll
    for (int j = 0; j < 16; j++) {
        const f4 ov = o[j];
        #pragma unroll
        for (int r = 0; r < 4; r++) {
            const size_t row = (size_t)b * SEQ + m0 + 16 * wp + 4 * lg + r;
            Out[row * DIM + 256 * h + 16 * j + lx] = ov[r] * il[r];
        }
    }
}

extern "C" void kernel_launch(void* const* d_in, const int* in_sizes, int n_in,
                              void* d_out, int out_size, void* d_ws, size_t ws_size,
                              hipStream_t stream) {
    const float* Q  = (const float*)d_in[0];
    const float* K  = (const float*)d_in[1];
    const float* V  = (const float*)d_in[2];
    const int*   mf = (const int*)d_in[3];
    float* O = (float*)d_out;

    dim3 grid(BATCH * (SEQ / 64));   // 256 blocks, 1 per CU
    dim3 block(NTH);
    attn_kernel<<<grid, block, 0, stream>>>(Q, K, V, mf, O);
}

// Round 9
// 409.131 us; speedup vs baseline: 1.1134x; 1.1134x over previous
//
#include <hip/hip_runtime.h>
#include <math.h>

#define BATCH 8
#define SEQ   2048
#define DIM   512
#define NTH   512

typedef unsigned int u32;
typedef _Float16 h2  __attribute__((ext_vector_type(2)));
typedef _Float16 h8  __attribute__((ext_vector_type(8)));
typedef float    f4  __attribute__((ext_vector_type(4)));
typedef u32      u4v __attribute__((ext_vector_type(4)));

#define MFMA16(a,b,c) __builtin_amdgcn_mfma_f32_16x16x32_f16((a),(b),(c),0,0,0)

#if __has_builtin(__builtin_amdgcn_cvt_pkrtz)
__device__ __forceinline__ u32 pack2(float a, float b) {
    return __builtin_bit_cast(u32, __builtin_amdgcn_cvt_pkrtz(a, b));
}
__device__ __forceinline__ void split2(float a, float b, u32& hi, u32& lo) {
    h2 th = __builtin_bit_cast(h2, __builtin_amdgcn_cvt_pkrtz(a, b));
    hi = __builtin_bit_cast(u32, th);
    lo = __builtin_bit_cast(u32, __builtin_amdgcn_cvt_pkrtz(a - (float)th[0], b - (float)th[1]));
}
#else
__device__ __forceinline__ u32 pack2(float a, float b) {
    h2 t; t[0] = (_Float16)a; t[1] = (_Float16)b;
    return __builtin_bit_cast(u32, t);
}
__device__ __forceinline__ void split2(float a, float b, u32& hi, u32& lo) {
    _Float16 ha = (_Float16)a, hb = (_Float16)b;
    h2 th; th[0] = ha; th[1] = hb; hi = __builtin_bit_cast(u32, th);
    h2 tl; tl[0] = (_Float16)(a - (float)ha); tl[1] = (_Float16)(b - (float)hb);
    lo = __builtin_bit_cast(u32, tl);
}
#endif

// 8 waves: wp=w&3 -> Q rows 16wp..+15; h=w>>2 -> d-half (QK k-split, PV d-split).
// Maps (R6/R7-validated): A row=lane&15, slot e<->k=8lg+e; B col=lane&15 same
// slots; C/D row=4lg+reg, col=lane&15.
__global__ __launch_bounds__(NTH, 2)
void attn_kernel(const float* __restrict__ Q, const float* __restrict__ K,
                 const float* __restrict__ V, const int* __restrict__ mfp,
                 float* __restrict__ Out)
{
    // K^T pair-packed per half-chunk (64 d/half/iter): [half][dp32][s128+pad]
    __shared__ u32 KTh[2][32][132];                            // 33.8 KB
    __shared__ u32 KTl[2][32][132];                            // 33.8 KB
    __shared__ union { float sx[64][132]; u32 vq[2][64][68]; } SV;  // 34.8 KB
    __shared__ u32  Pp[64][68];                                // 17.4 KB
    __shared__ float fsx[64];
    __shared__ float lsx[64];

    const int tid  = threadIdx.x;
    const int w    = tid >> 6;
    const int wp   = w & 3;
    const int h    = w >> 2;           // == tid>>8; also staging half
    const int lane = tid & 63;
    const int lx   = lane & 15;
    const int lg   = lane >> 4;
    const int b    = blockIdx.x >> 5;
    const int m0   = (blockIdx.x & 31) * 64;
    const int mf   = mfp[0];

    // staging maps (each half staged by its own 4 waves; h == tid>>8)
    const int krow = (tid >> 1) & 127;  // 32-run per wave -> 2-way write banks
    const int ksc  = tid & 1;           // 32-d subspan of the 64-d chunk
    const int vsp  = (tid >> 2) & 63;   // s-pair row
    const int vdg  = tid & 3;           // 16-d group within 64-d chunk

    const float* __restrict__ Qb = Q + (size_t)b * SEQ * DIM;
    const float* __restrict__ Kb = K + (size_t)b * SEQ * DIM;
    const float* __restrict__ Vb = V + (size_t)b * SEQ * DIM;

    // ---- Q fragments in registers (own d-half, hi/lo split): 64 VGPR ----
    h8 qh[8], ql[8];
    {
        const float* qrowp = Qb + (size_t)(m0 + 16 * wp + lx) * DIM;
        #pragma unroll
        for (int t = 0; t < 8; t++) {
            float bufv[8];
            *(float4*)&bufv[0] = *(const float4*)(qrowp + 256 * h + 32 * t + 8 * lg);
            *(float4*)&bufv[4] = *(const float4*)(qrowp + 256 * h + 32 * t + 8 * lg + 4);
            u4v uh, ul;
            #pragma unroll
            for (int p = 0; p < 4; p++) {
                u32 hi, lo; split2(bufv[2*p], bufv[2*p+1], hi, lo);
                uh[p] = hi; ul[p] = lo;
            }
            qh[t] = __builtin_bit_cast(h8, uh);
            ql[t] = __builtin_bit_cast(h8, ul);
        }
    }

    f4 o[16];
    const f4 fz = {0.f, 0.f, 0.f, 0.f};
    #pragma unroll
    for (int i = 0; i < 16; i++) o[i] = fz;
    float m_run[4] = {-INFINITY, -INFINITY, -INFINITY, -INFINITY};
    float l_run[4] = {0.f, 0.f, 0.f, 0.f};

    const float dk = 22.627416997969522f;   // sqrt(512)

    for (int s0 = 0; s0 < SEQ; s0 += 128) {
        // ============ S = Q K^T partial over own 256-d half ============
        f4 sa[8];
        #pragma unroll
        for (int nt = 0; nt < 8; nt++) sa[nt] = fz;

        f4 kreg[8];
        #pragma unroll
        for (int c = 0; c < 8; c++)
            kreg[c] = *(const f4*)(Kb + (size_t)(s0 + krow) * DIM + 256 * h + 32 * ksc + 4 * c);

        #pragma unroll
        for (int i = 0; i < 4; i++) {
            if (i) __syncthreads();   // (A) prior readers of KT done
            #pragma unroll
            for (int c = 0; c < 8; c++) {
                u32 hA, lA, hB, lB;
                split2(kreg[c][0], kreg[c][1], hA, lA);
                split2(kreg[c][2], kreg[c][3], hB, lB);
                const int dp = 16 * ksc + 2 * c;
                KTh[h][dp][krow]     = hA;   // bank = (4dp+krow)%32: 2-way, free
                KTh[h][dp + 1][krow] = hB;
                KTl[h][dp][krow]     = lA;
                KTl[h][dp + 1][krow] = lB;
            }
            __syncthreads();          // (B) staged chunk visible
            if (i < 3) {              // register prefetch of next 64-d chunk
                #pragma unroll
                for (int c = 0; c < 8; c++)
                    kreg[c] = *(const f4*)(Kb + (size_t)(s0 + krow) * DIM
                                           + 256 * h + 64 * (i + 1) + 32 * ksc + 4 * c);
            }
            __builtin_amdgcn_s_setprio(1);
            #pragma unroll
            for (int tl = 0; tl < 2; tl++) {
                const int t = 2 * i + tl;
                #pragma unroll
                for (int nt = 0; nt < 8; nt++) {
                    u4v uh, ul;
                    #pragma unroll
                    for (int p = 0; p < 4; p++) {
                        uh[p] = KTh[h][16 * tl + 4 * lg + p][16 * nt + lx];  // 2-way: free
                        ul[p] = KTl[h][16 * tl + 4 * lg + p][16 * nt + lx];
                    }
                    const h8 kh = __builtin_bit_cast(h8, uh);
                    const h8 kl = __builtin_bit_cast(h8, ul);
                    sa[nt] = MFMA16(qh[t], kh, sa[nt]);
                    sa[nt] = MFMA16(qh[t], kl, sa[nt]);
                    sa[nt] = MFMA16(ql[t], kh, sa[nt]);
                }
            }
            __builtin_amdgcn_s_setprio(0);
        }

        // V prefetch for PV iter 0 (overlaps the whole softmax phase)
        f4 vreg[2][4];
        #pragma unroll
        for (int r = 0; r < 2; r++)
            #pragma unroll
            for (int c2 = 0; c2 < 4; c2++)
                vreg[r][c2] = *(const f4*)(Vb + (size_t)(s0 + 2 * vsp + r) * DIM
                                           + 256 * h + 16 * vdg + 4 * c2);

        // ============ S-merge + softmax (h1 owns), validated math ============
        if (h == 0) {
            #pragma unroll
            for (int nt = 0; nt < 8; nt++)
                #pragma unroll
                for (int r = 0; r < 4; r++)
                    SV.sx[16 * wp + 4 * lg + r][16 * nt + lx] = sa[nt][r];
        }
        __syncthreads();   // (C)

        float fscale[4];
        if (h == 1) {
            float pw[4][8];
            #pragma unroll
            for (int nt = 0; nt < 8; nt++)
                #pragma unroll
                for (int r = 0; r < 4; r++) {
                    float s = sa[nt][r] + SV.sx[16 * wp + 4 * lg + r][16 * nt + lx];
                    s = (s == s) ? s : 0.0f;                       // NaN scrub
                    sa[nt][r] = fminf(fmaxf(s, -2.0e4f), 2.0e4f);  // overflow-proof
                }
            #pragma unroll
            for (int r = 0; r < 4; r++) {
                const int tg = m0 + 16 * wp + 4 * lg + r;
                float z[8]; float zm = -INFINITY;
                #pragma unroll
                for (int nt = 0; nt < 8; nt++) {
                    const int sg = s0 + nt * 16 + lx;
                    const float mult = (mf && sg >= tg) ? -1.0e9f : 1.0f;
                    z[nt] = sa[nt][r] * mult / dk;
                    zm = fmaxf(zm, z[nt]);
                }
                #pragma unroll
                for (int mm = 1; mm < 16; mm <<= 1) zm = fmaxf(zm, __shfl_xor(zm, mm));
                const float mnew = fmaxf(m_run[r], zm);
                float ps = 0.f;
                #pragma unroll
                for (int nt = 0; nt < 8; nt++) {
                    const float p = __expf(z[nt] - mnew);
                    pw[r][nt] = p; ps += p;
                }
                #pragma unroll
                for (int mm = 1; mm < 16; mm <<= 1) ps += __shfl_xor(ps, mm);
                const float fs = __expf(m_run[r] - mnew);   // first tile: 0
                fscale[r] = fs;
                l_run[r]  = l_run[r] * fs + ps;
                m_run[r]  = mnew;
                if (lx == 0) fsx[16 * wp + 4 * lg + r] = fs;
            }
            #pragma unroll
            for (int r = 0; r < 4; r++)
                #pragma unroll
                for (int nt = 0; nt < 8; nt++) {
                    const float self = pw[r][nt];
                    const float nb   = __shfl_xor(self, 1);
                    if (!(lx & 1))
                        Pp[16 * wp + 4 * lg + r][8 * nt + (lx >> 1)] = pack2(self, nb);
                }
        }
        __syncthreads();   // (D) Pp + fsx visible; sx reads done (vq overlay safe)

        if (h == 0) {
            #pragma unroll
            for (int r = 0; r < 4; r++) fscale[r] = fsx[16 * wp + 4 * lg + r];
        }
        #pragma unroll
        for (int i = 0; i < 16; i++) {
            f4 t = o[i];
            t[0] *= fscale[0]; t[1] *= fscale[1]; t[2] *= fscale[2]; t[3] *= fscale[3];
            o[i] = t;
        }

        // ============ O += P V over own d-half (64-d chunks) ============
        h8 pa[4];
        #pragma unroll
        for (int dv = 0; dv < 4; dv++) {
            if (dv) __syncthreads();   // (E) prior readers of vq done
            #pragma unroll
            for (int e = 0; e < 16; e++) {
                const int c2 = e >> 2, el = e & 3;
                SV.vq[h][vsp][16 * vdg + e] = pack2(vreg[0][c2][el], vreg[1][c2][el]);
            }
            __syncthreads();           // (F) staged V chunk visible
            if (dv < 3) {
                #pragma unroll
                for (int r = 0; r < 2; r++)
                    #pragma unroll
                    for (int c2 = 0; c2 < 4; c2++)
                        vreg[r][c2] = *(const f4*)(Vb + (size_t)(s0 + 2 * vsp + r) * DIM
                                                   + 256 * h + 64 * (dv + 1) + 16 * vdg + 4 * c2);
            }
            if (dv == 0) {
                #pragma unroll
                for (int k4 = 0; k4 < 4; k4++)
                    pa[k4] = __builtin_bit_cast(h8,
                        *(const u4v*)&Pp[16 * wp + lx][16 * k4 + 4 * lg]);
            }
            __builtin_amdgcn_s_setprio(1);
            #pragma unroll
            for (int dt = 0; dt < 4; dt++) {
                #pragma unroll
                for (int k4 = 0; k4 < 4; k4++) {
                    u4v uv;
                    #pragma unroll
                    for (int p = 0; p < 4; p++)
                        uv[p] = SV.vq[h][16 * k4 + 4 * lg + p][16 * dt + lx];  // 2-way: free
                    o[4 * dv + dt] = MFMA16(pa[k4], __builtin_bit_cast(h8, uv), o[4 * dv + dt]);
                }
            }
            __builtin_amdgcn_s_setprio(0);
        }
    }

    // ================= epilogue: O / l =================
    if (h == 1) {
        #pragma unroll
        for (int r = 0; r < 4; r++)
            if (lx == 0) lsx[16 * wp + 4 * lg + r] = l_run[r];
    }
    __syncthreads();
    float il[4];
    #pragma unroll
    for (int r = 0; r < 4; r++)
        il[r] = 1.0f / ((h == 1) ? l_run[r] : lsx[16 * wp + 4 * lg + r]);
    #pragma unroll
    for (int j = 0; j < 16; j++) {
        const f4 ov = o[j];
        #pragma unroll
        for (int r = 0; r < 4; r++) {
            const size_t row = (size_t)b * SEQ + m0 + 16 * wp + 4 * lg + r;
            Out[row * DIM + 256 * h + 16 * j + lx] = ov[r] * il[r];
        }
    }
}

extern "C" void kernel_launch(void* const* d_in, const int* in_sizes, int n_in,
                              void* d_out, int out_size, void* d_ws, size_t ws_size,
                              hipStream_t stream) {
    const float* Q  = (const float*)d_in[0];
    const float* K  = (const float*)d_in[1];
    const float* V  = (const float*)d_in[2];
    const int*   mf = (const int*)d_in[3];
    float* O = (float*)d_out;

    dim3 grid(BATCH * (SEQ / 64));   // 256 blocks, 1 per CU
    dim3 block(NTH);
    attn_kernel<<<grid, block, 0, stream>>>(Q, K, V, mf, O);
}